// Round 5
// baseline (203.909 us; speedup 1.0000x reference)
//
#include <hip/hip_runtime.h>
#include <math.h>

// Problem constants: B=8, N=2048, D=512, S=4096
#define BATCH 8
#define NNODES 2048
#define DDIM 512
#define SWAPS 4096
#define M_TOTAL (BATCH * SWAPS)   // 32768
#define MD (BATCH * NNODES)       // 16384 dense rows
#define KD DDIM                   // 512 (dense GEMM K)
#define ND (4 * DDIM)             // 2048 (dense GEMM N = 4 segs x 512)
#define K2 DDIM                   // 512
#define N2 (DDIM / 2)             // 256

typedef __attribute__((ext_vector_type(8))) __bf16 bf16x8;   // MFMA A/B frag
typedef __attribute__((ext_vector_type(4))) float f32x4;      // MFMA C/D frag
typedef __attribute__((ext_vector_type(8))) unsigned short us8;
typedef unsigned short ushort_t;

__device__ __forceinline__ float gelu_exact(float x) {
    return 0.5f * x * (1.0f + erff(x * 0.70710678118654752440f));
}
__device__ __forceinline__ float softplus_f(float x) {
    return fmaxf(x, 0.0f) + log1pf(expf(-fabsf(x)));
}
__device__ __forceinline__ unsigned short f2bf(float f) {
    unsigned int u = __builtin_bit_cast(unsigned int, f);
    u += 0x7FFFu + ((u >> 16) & 1u);
    return (unsigned short)(u >> 16);
}
__device__ __forceinline__ float bf2f(unsigned short s) {
    return __builtin_bit_cast(float, (unsigned int)s << 16);
}
__device__ __forceinline__ void glds16(const void* g, void* l) {
    __builtin_amdgcn_global_load_lds(
        (const __attribute__((address_space(1))) void*)g,
        (__attribute__((address_space(3))) void*)l, 16, 0, 0);
}

// ---------------------------------------------------------------------------
// convert: h -> h_bf (bf16);  W1[k][n] -> W1pt[j][d] bf16, j=(k/512)*512+n,
// d=k%512 (K-major for dense GEMM);  W2 -> W2t bf16 K-major.
// ---------------------------------------------------------------------------
__global__ __launch_bounds__(256) void convert_kernel(
    const float* __restrict__ h, const float* __restrict__ W1,
    const float* __restrict__ W2, ushort_t* __restrict__ h_bf,
    ushort_t* __restrict__ W1pt, ushort_t* __restrict__ W2t)
{
    const int bid = blockIdx.x;
    if (bid < 8192) {                       // h: 8M elems
        size_t i = ((size_t)bid * 256 + threadIdx.x) * 4;
        float4 v = *(const float4*)(h + i);
        ushort4 o = { f2bf(v.x), f2bf(v.y), f2bf(v.z), f2bf(v.w) };
        *(ushort4*)(h_bf + i) = o;
    } else if (bid < 8192 + 1024) {         // W1: 1M elems (2048 x 512 row-major)
        size_t e = ((size_t)(bid - 8192) * 256 + threadIdx.x) * 4;
        const int k = (int)(e >> 9), n = (int)(e & 511);
        const int sg = k >> 9, d = k & 511;
        const int j = sg * 512 + n;
        float4 v = *(const float4*)(W1 + e);
        W1pt[(size_t)(j + 0) * KD + d] = f2bf(v.x);
        W1pt[(size_t)(j + 1) * KD + d] = f2bf(v.y);
        W1pt[(size_t)(j + 2) * KD + d] = f2bf(v.z);
        W1pt[(size_t)(j + 3) * KD + d] = f2bf(v.w);
    } else {                                // W2: 131072 elems (512 x 256)
        size_t e = ((size_t)(bid - 9216) * 256 + threadIdx.x) * 4;
        const int k = (int)(e >> 8), n = (int)(e & 255);
        float4 v = *(const float4*)(W2 + e);
        W2t[(size_t)(n + 0) * K2 + k] = f2bf(v.x);
        W2t[(size_t)(n + 1) * K2 + k] = f2bf(v.y);
        W2t[(size_t)(n + 2) * K2 + k] = f2bf(v.z);
        W2t[(size_t)(n + 3) * K2 + k] = f2bf(v.w);
    }
}

// ---------------------------------------------------------------------------
// Dense GEMM1: P[m][j] = bf16( h_bf[m,:] @ W1pt[j,:] ), M=16384, N=2048, K=512.
// m97-pattern 128x128 tile, BK=32, XCD swizzle (bid&7 = batch).
// ---------------------------------------------------------------------------
__global__ __launch_bounds__(256) void gemm1_dense(
    const ushort_t* __restrict__ h_bf, const ushort_t* __restrict__ W1pt,
    ushort_t* __restrict__ P)
{
    __shared__ __align__(16) char smem[16384];   // A 8KB @0, B 8KB @8192

    const int tid = threadIdx.x;
    const int w = tid >> 6, lane = tid & 63;
    const int quad = lane >> 4, l16 = lane & 15;
    const int wr = w >> 1, wc = w & 1;

    const int bid = blockIdx.x;
    const int xcd = bid & 7;
    const int r = bid >> 3;
    const int m0 = xcd * NNODES + (r & 15) * 128;
    const int n0 = (r >> 4) * 128;

    const int row0 = tid >> 2, sub = tid & 3;
    const int cg = (sub - (row0 >> 1)) & 3;
    const ushort_t* bA0 = h_bf + (size_t)(m0 + row0) * KD + cg * 8;
    const ushort_t* bA1 = h_bf + (size_t)(m0 + row0 + 64) * KD + cg * 8;
    const ushort_t* bB0 = W1pt + (size_t)(n0 + row0) * KD + cg * 8;
    const ushort_t* bB1 = W1pt + (size_t)(n0 + row0 + 64) * KD + cg * 8;

    char* ldsA0 = smem + w * 1024;
    char* ldsA1 = smem + 4096 + w * 1024;
    char* ldsB0 = smem + 8192 + w * 1024;
    char* ldsB1 = smem + 12288 + w * 1024;

    int pa[4], pb[4];
    #pragma unroll
    for (int i = 0; i < 4; ++i) {
        const int rA = wr * 64 + i * 16 + l16;
        const int rB = wc * 64 + i * 16 + l16;
        pa[i] = rA * 64 + (((quad + (rA >> 1)) & 3) * 16);
        pb[i] = 8192 + rB * 64 + (((quad + (rB >> 1)) & 3) * 16);
    }

    f32x4 acc[4][4] = {};

    for (int kt = 0; kt < 16; ++kt) {
        const int oo = kt * 32;
        glds16(bA0 + oo, ldsA0);
        glds16(bA1 + oo, ldsA1);
        glds16(bB0 + oo, ldsB0);
        glds16(bB1 + oo, ldsB1);
        __syncthreads();
        bf16x8 af[4], bfr[4];
        #pragma unroll
        for (int i = 0; i < 4; ++i) {
            af[i]  = *(const bf16x8*)(smem + pa[i]);
            bfr[i] = *(const bf16x8*)(smem + pb[i]);
        }
        #pragma unroll
        for (int i = 0; i < 4; ++i)
            #pragma unroll
            for (int jj = 0; jj < 4; ++jj)
                acc[i][jj] = __builtin_amdgcn_mfma_f32_16x16x32_bf16(
                    af[i], bfr[jj], acc[i][jj], 0, 0, 0);
        __syncthreads();
    }

    #pragma unroll
    for (int jj = 0; jj < 4; ++jj) {
        const int n = n0 + wc * 64 + jj * 16 + l16;
        #pragma unroll
        for (int i = 0; i < 4; ++i) {
            f32x4 v = acc[i][jj];
            #pragma unroll
            for (int rr = 0; rr < 4; ++rr) {
                const int m = m0 + wr * 64 + i * 16 + quad * 4 + rr;
                P[(size_t)m * ND + n] = f2bf(v[rr]);
            }
        }
    }
}

// ---------------------------------------------------------------------------
// gather_sum: x1[m][n] = bf16(gelu( b1[n] + sum_sg P[b, idx[m][sg], sg*512+n] ))
// One wave per swap row; lane covers n = lane*8..+7.
// ---------------------------------------------------------------------------
__global__ __launch_bounds__(256) void gather_sum_kernel(
    const ushort_t* __restrict__ P, const int* __restrict__ idx,
    const float* __restrict__ b1, ushort_t* __restrict__ x1_bf)
{
    const int wave = threadIdx.x >> 6, lane = threadIdx.x & 63;
    const int m = blockIdx.x * 4 + wave;
    const int b = m >> 12;
    const int4 iv = *(const int4*)(idx + (size_t)m * 4);
    const ushort_t* Pb = P + (size_t)b * NNODES * ND;
    const int n = lane * 8;

    float s[8];
    {
        float4 ba = *(const float4*)(b1 + n);
        float4 bb = *(const float4*)(b1 + n + 4);
        s[0] = ba.x; s[1] = ba.y; s[2] = ba.z; s[3] = ba.w;
        s[4] = bb.x; s[5] = bb.y; s[6] = bb.z; s[7] = bb.w;
    }
    const int nodes[4] = { iv.x, iv.y, iv.z, iv.w };
    #pragma unroll
    for (int sg = 0; sg < 4; ++sg) {
        us8 v = *(const us8*)(Pb + (size_t)nodes[sg] * ND + sg * 512 + n);
        #pragma unroll
        for (int t = 0; t < 8; ++t) s[t] += bf2f(v[t]);
    }
    ushort4 o0 = { f2bf(gelu_exact(s[0])), f2bf(gelu_exact(s[1])),
                   f2bf(gelu_exact(s[2])), f2bf(gelu_exact(s[3])) };
    ushort4 o1 = { f2bf(gelu_exact(s[4])), f2bf(gelu_exact(s[5])),
                   f2bf(gelu_exact(s[6])), f2bf(gelu_exact(s[7])) };
    *(ushort4*)(x1_bf + (size_t)m * K2 + n) = o0;
    *(ushort4*)(x1_bf + (size_t)m * K2 + n + 4) = o1;
}

// ---------------------------------------------------------------------------
// GEMM2 + partial head: same proven GEMM body (128x128, K=512); epilogue
// computes partial[m] = sum_{n in block cols} gelu(acc+b2[n]) * W3[n],
// reduced in-register (shfl over l16) + LDS (wave-column halves), written to
// pp[half][m]. No x2 materialization.
// ---------------------------------------------------------------------------
__global__ __launch_bounds__(256) void gemm2_partial(
    const ushort_t* __restrict__ x1_bf, const ushort_t* __restrict__ W2t,
    const float* __restrict__ b2, const float* __restrict__ W3,
    float* __restrict__ pp)
{
    __shared__ __align__(16) char smem[16384];

    const int tid = threadIdx.x;
    const int w = tid >> 6, lane = tid & 63;
    const int quad = lane >> 4, l16 = lane & 15;
    const int wr = w >> 1, wc = w & 1;
    const int m0 = blockIdx.y * 128, n0 = blockIdx.x * 128;

    const int row0 = tid >> 2, sub = tid & 3;
    const int cg = (sub - (row0 >> 1)) & 3;
    const ushort_t* bA0 = x1_bf + (size_t)(m0 + row0) * K2 + cg * 8;
    const ushort_t* bA1 = x1_bf + (size_t)(m0 + row0 + 64) * K2 + cg * 8;
    const ushort_t* bB0 = W2t + (size_t)(n0 + row0) * K2 + cg * 8;
    const ushort_t* bB1 = W2t + (size_t)(n0 + row0 + 64) * K2 + cg * 8;

    char* ldsA0 = smem + w * 1024;
    char* ldsA1 = smem + 4096 + w * 1024;
    char* ldsB0 = smem + 8192 + w * 1024;
    char* ldsB1 = smem + 12288 + w * 1024;

    int pa[4], pb[4];
    #pragma unroll
    for (int i = 0; i < 4; ++i) {
        const int rA = wr * 64 + i * 16 + l16;
        const int rB = wc * 64 + i * 16 + l16;
        pa[i] = rA * 64 + (((quad + (rA >> 1)) & 3) * 16);
        pb[i] = 8192 + rB * 64 + (((quad + (rB >> 1)) & 3) * 16);
    }

    f32x4 acc[4][4] = {};

    for (int kt = 0; kt < 16; ++kt) {
        const int oo = kt * 32;
        glds16(bA0 + oo, ldsA0);
        glds16(bA1 + oo, ldsA1);
        glds16(bB0 + oo, ldsB0);
        glds16(bB1 + oo, ldsB1);
        __syncthreads();
        bf16x8 af[4], bfr[4];
        #pragma unroll
        for (int i = 0; i < 4; ++i) {
            af[i]  = *(const bf16x8*)(smem + pa[i]);
            bfr[i] = *(const bf16x8*)(smem + pb[i]);
        }
        #pragma unroll
        for (int i = 0; i < 4; ++i)
            #pragma unroll
            for (int jj = 0; jj < 4; ++jj)
                acc[i][jj] = __builtin_amdgcn_mfma_f32_16x16x32_bf16(
                    af[i], bfr[jj], acc[i][jj], 0, 0, 0);
        __syncthreads();
    }

    // ---- fused epilogue: partial head dot over this block's 128 cols ----
    float w3r[4], b2r[4];
    #pragma unroll
    for (int jj = 0; jj < 4; ++jj) {
        const int n = n0 + wc * 64 + jj * 16 + l16;
        w3r[jj] = W3[n];
        b2r[jj] = b2[n];
    }
    float part[4][4];   // [i][r]
    #pragma unroll
    for (int i = 0; i < 4; ++i)
        #pragma unroll
        for (int rr = 0; rr < 4; ++rr) part[i][rr] = 0.0f;
    #pragma unroll
    for (int i = 0; i < 4; ++i)
        #pragma unroll
        for (int jj = 0; jj < 4; ++jj) {
            f32x4 v = acc[i][jj];
            #pragma unroll
            for (int rr = 0; rr < 4; ++rr)
                part[i][rr] = fmaf(gelu_exact(v[rr] + b2r[jj]), w3r[jj], part[i][rr]);
        }
    // reduce across the 16 l16 lanes (cols); rows live in (quad, rr)
    #pragma unroll
    for (int off = 1; off < 16; off <<= 1)
        #pragma unroll
        for (int i = 0; i < 4; ++i)
            #pragma unroll
            for (int rr = 0; rr < 4; ++rr)
                part[i][rr] += __shfl_xor(part[i][rr], off);

    // combine the two wave-column halves via LDS (staging reads all done)
    float* red = (float*)smem;
    __syncthreads();
    if (wc == 1 && l16 == 0) {
        #pragma unroll
        for (int i = 0; i < 4; ++i)
            #pragma unroll
            for (int rr = 0; rr < 4; ++rr)
                red[wr * 64 + i * 16 + quad * 4 + rr] = part[i][rr];
    }
    __syncthreads();
    if (wc == 0 && l16 == 0) {
        float* dst = pp + (size_t)blockIdx.x * M_TOTAL + m0;
        #pragma unroll
        for (int i = 0; i < 4; ++i)
            #pragma unroll
            for (int rr = 0; rr < 4; ++rr) {
                const int r2 = wr * 64 + i * 16 + quad * 4 + rr;
                dst[r2] = part[i][rr] + red[r2];
            }
    }
}

// ---------------------------------------------------------------------------
// finalize: out[m] = softplus( pp[0][m] + pp[1][m] + b3 )
// ---------------------------------------------------------------------------
__global__ __launch_bounds__(256) void finalize_head(
    const float* __restrict__ pp, const float* __restrict__ b3,
    float* __restrict__ out)
{
    const int m = blockIdx.x * 256 + threadIdx.x;
    out[m] = softplus_f(pp[m] + pp[M_TOTAL + m] + b3[0]);
}

// ---------------------------------------------------------------------------
// Workspace layout (aliased; peak 96.25 MB):
//   P     @ 0      : 64 MB  (dead after gather_sum)
//   pp    @ 0      : 2*32768*4 = 256 KB (overlays dead P)
//   h_bf  @ 64 MB  : 16 MB  (dead after gemm1_dense)
//   W1pt  @ 80 MB  :  2 MB  (dead after gemm1_dense)
//   x1_bf @ 64 MB  : 32 MB  (overlays dead h_bf/W1pt)
//   W2t   @ 96 MB  : 256 KB
// ---------------------------------------------------------------------------
extern "C" void kernel_launch(void* const* d_in, const int* in_sizes, int n_in,
                              void* d_out, int out_size, void* d_ws, size_t ws_size,
                              hipStream_t stream) {
    const float* h   = (const float*)d_in[0];
    const int*   idx = (const int*)d_in[1];
    const float* W1  = (const float*)d_in[2];
    const float* b1  = (const float*)d_in[3];
    const float* W2  = (const float*)d_in[4];
    const float* b2  = (const float*)d_in[5];
    const float* W3  = (const float*)d_in[6];
    const float* b3  = (const float*)d_in[7];
    float* out = (float*)d_out;

    char* ws = (char*)d_ws;
    ushort_t* P     = (ushort_t*)ws;
    float*    pp    = (float*)ws;
    ushort_t* h_bf  = (ushort_t*)(ws + (64u << 20));
    ushort_t* W1pt  = (ushort_t*)(ws + (80u << 20));
    ushort_t* x1_bf = (ushort_t*)(ws + (64u << 20));
    ushort_t* W2t   = (ushort_t*)(ws + (96u << 20));

    convert_kernel<<<9344, 256, 0, stream>>>(h, W1, W2, h_bf, W1pt, W2t);
    gemm1_dense<<<2048, 256, 0, stream>>>(h_bf, W1pt, P);
    gather_sum_kernel<<<M_TOTAL / 4, 256, 0, stream>>>(P, idx, b1, x1_bf);
    gemm2_partial<<<dim3(N2 / 128, M_TOTAL / 128), 256, 0, stream>>>(x1_bf, W2t, b2, W3, pp);
    finalize_head<<<M_TOTAL / 256, 256, 0, stream>>>(pp, b3, out);
}

// Round 7
// 202.576 us; speedup vs baseline: 1.0066x; 1.0066x over previous
//
#include <hip/hip_runtime.h>
#include <math.h>

// Problem constants: B=8, N=2048, D=512, S=4096
#define BATCH 8
#define NNODES 2048
#define DDIM 512
#define SWAPS 4096
#define M_TOTAL (BATCH * SWAPS)   // 32768
#define KD DDIM                   // 512 (dense GEMM K)
#define ND (4 * DDIM)             // 2048 (dense GEMM N = 4 segs x 512)
#define K2 DDIM                   // 512
#define N2 (DDIM / 2)             // 256

typedef __attribute__((ext_vector_type(8))) __bf16 bf16x8;   // MFMA A/B frag
typedef __attribute__((ext_vector_type(4))) float f32x4;      // MFMA C/D frag
typedef __attribute__((ext_vector_type(8))) unsigned short us8;
typedef unsigned short ushort_t;

__device__ __forceinline__ float gelu_exact(float x) {
    return 0.5f * x * (1.0f + erff(x * 0.70710678118654752440f));
}
__device__ __forceinline__ float softplus_f(float x) {
    return fmaxf(x, 0.0f) + log1pf(expf(-fabsf(x)));
}
__device__ __forceinline__ unsigned short f2bf(float f) {
    unsigned int u = __builtin_bit_cast(unsigned int, f);
    u += 0x7FFFu + ((u >> 16) & 1u);
    return (unsigned short)(u >> 16);
}
__device__ __forceinline__ float bf2f(unsigned short s) {
    return __builtin_bit_cast(float, (unsigned int)s << 16);
}
__device__ __forceinline__ void glds16(const void* g, void* l) {
    __builtin_amdgcn_global_load_lds(
        (const __attribute__((address_space(1))) void*)g,
        (__attribute__((address_space(3))) void*)l, 16, 0, 0);
}

// ---------------------------------------------------------------------------
// convert: h -> h_bf (bf16);  W1[k][n] -> W1pt[j][d] bf16, j=(k/512)*512+n,
// d=k%512 (K-major for dense GEMM);  W2 -> W2t bf16 K-major.
// ---------------------------------------------------------------------------
__global__ __launch_bounds__(256) void convert_kernel(
    const float* __restrict__ h, const float* __restrict__ W1,
    const float* __restrict__ W2, ushort_t* __restrict__ h_bf,
    ushort_t* __restrict__ W1pt, ushort_t* __restrict__ W2t)
{
    const int bid = blockIdx.x;
    if (bid < 8192) {                       // h: 8M elems
        size_t i = ((size_t)bid * 256 + threadIdx.x) * 4;
        float4 v = *(const float4*)(h + i);
        ushort4 o = { f2bf(v.x), f2bf(v.y), f2bf(v.z), f2bf(v.w) };
        *(ushort4*)(h_bf + i) = o;
    } else if (bid < 8192 + 1024) {         // W1: 1M elems (2048 x 512 row-major)
        size_t e = ((size_t)(bid - 8192) * 256 + threadIdx.x) * 4;
        const int k = (int)(e >> 9), n = (int)(e & 511);
        const int sg = k >> 9, d = k & 511;
        const int j = sg * 512 + n;
        float4 v = *(const float4*)(W1 + e);
        W1pt[(size_t)(j + 0) * KD + d] = f2bf(v.x);
        W1pt[(size_t)(j + 1) * KD + d] = f2bf(v.y);
        W1pt[(size_t)(j + 2) * KD + d] = f2bf(v.z);
        W1pt[(size_t)(j + 3) * KD + d] = f2bf(v.w);
    } else {                                // W2: 131072 elems (512 x 256)
        size_t e = ((size_t)(bid - 9216) * 256 + threadIdx.x) * 4;
        const int k = (int)(e >> 8), n = (int)(e & 255);
        float4 v = *(const float4*)(W2 + e);
        W2t[(size_t)(n + 0) * K2 + k] = f2bf(v.x);
        W2t[(size_t)(n + 1) * K2 + k] = f2bf(v.y);
        W2t[(size_t)(n + 2) * K2 + k] = f2bf(v.z);
        W2t[(size_t)(n + 3) * K2 + k] = f2bf(v.w);
    }
}

// ---------------------------------------------------------------------------
// Dense GEMM1: M=16384, N=2048, K=512; 128x128 tile; TWO BK=32 K-tiles staged
// per barrier pair (32KB LDS) -> 16 sync pairs instead of 32.
// Output layout P2[b][nc][node][sg*256+pos]: per-(b,nc) region = 4MB = 1 XCD L2,
// so the gather pass is L2-resident. XCD swizzle: bid&7 = batch.
// ---------------------------------------------------------------------------
__global__ __launch_bounds__(256) void gemm1_dense(
    const ushort_t* __restrict__ h_bf, const ushort_t* __restrict__ W1pt,
    ushort_t* __restrict__ P2)
{
    __shared__ __align__(16) char smem[32768];  // [A0 8K][B0 8K] @0, same @16384

    const int tid = threadIdx.x;
    const int w = tid >> 6, lane = tid & 63;
    const int quad = lane >> 4, l16 = lane & 15;
    const int wr = w >> 1, wc = w & 1;

    const int bid = blockIdx.x;
    const int xcd = bid & 7;            // == batch
    const int r = bid >> 3;
    const int m0 = xcd * NNODES + (r & 15) * 128;
    const int n0 = (r >> 4) * 128;

    const int row0 = tid >> 2, sub = tid & 3;
    const int cg = (sub - (row0 >> 1)) & 3;
    const ushort_t* bA0 = h_bf + (size_t)(m0 + row0) * KD + cg * 8;
    const ushort_t* bA1 = h_bf + (size_t)(m0 + row0 + 64) * KD + cg * 8;
    const ushort_t* bB0 = W1pt + (size_t)(n0 + row0) * KD + cg * 8;
    const ushort_t* bB1 = W1pt + (size_t)(n0 + row0 + 64) * KD + cg * 8;

    int pa[4], pb[4];
    #pragma unroll
    for (int i = 0; i < 4; ++i) {
        const int rA = wr * 64 + i * 16 + l16;
        const int rB = wc * 64 + i * 16 + l16;
        pa[i] = rA * 64 + (((quad + (rA >> 1)) & 3) * 16);
        pb[i] = 8192 + rB * 64 + (((quad + (rB >> 1)) & 3) * 16);
    }

    f32x4 acc[4][4] = {};

    auto stage = [&](int kt, int half) {
        const int oo = kt * 32;
        char* base = smem + half * 16384;
        glds16(bA0 + oo, base + w * 1024);
        glds16(bA1 + oo, base + 4096 + w * 1024);
        glds16(bB0 + oo, base + 8192 + w * 1024);
        glds16(bB1 + oo, base + 12288 + w * 1024);
    };
    auto compute = [&](int half) {
        const char* base = smem + half * 16384;
        bf16x8 af[4], bfr[4];
        #pragma unroll
        for (int i = 0; i < 4; ++i) {
            af[i]  = *(const bf16x8*)(base + pa[i]);
            bfr[i] = *(const bf16x8*)(base + pb[i]);
        }
        #pragma unroll
        for (int i = 0; i < 4; ++i)
            #pragma unroll
            for (int jj = 0; jj < 4; ++jj)
                acc[i][jj] = __builtin_amdgcn_mfma_f32_16x16x32_bf16(
                    af[i], bfr[jj], acc[i][jj], 0, 0, 0);
    };

    for (int kt = 0; kt < 16; kt += 2) {
        stage(kt, 0);
        stage(kt + 1, 1);
        __syncthreads();
        compute(0);
        compute(1);
        __syncthreads();
    }

    // epilogue: write P2[(b*2+nc)][node][sg*256+pos]
    // j in [0,2048): sg = j>>9, nh = j&511, nc = nh>>8, pos = nh&255
    #pragma unroll
    for (int jj = 0; jj < 4; ++jj) {
        const int j = n0 + wc * 64 + jj * 16 + l16;
        const int sg = j >> 9, nh = j & 511;
        const size_t base = ((size_t)(xcd * 2 + (nh >> 8)) * NNODES) * 1024
                          + (size_t)(sg << 8) + (nh & 255);
        #pragma unroll
        for (int i = 0; i < 4; ++i) {
            f32x4 v = acc[i][jj];
            #pragma unroll
            for (int rr = 0; rr < 4; ++rr) {
                const int node = (m0 + wr * 64 + i * 16 + quad * 4 + rr) & (NNODES - 1);
                P2[base + (size_t)node * 1024] = f2bf(v[rr]);
            }
        }
    }
}

// ---------------------------------------------------------------------------
// gather (L2-resident): x1[m][nc*256+c] = bf16(gelu(b1 + sum_sg P2[b][nc][idx][sg*256+c]))
// bid = ((nc*512 + rg)*8 + b): XCD = b, nc slowest -> per XCD, pass nc=0
// completes (4MB region resident in its L2) before nc=1 begins.
// x1 stores non-temporal so the write stream doesn't evict P2 from L2.
// ---------------------------------------------------------------------------
__global__ __launch_bounds__(256) void gather_sum_kernel(
    const ushort_t* __restrict__ P2, const int* __restrict__ idx,
    const float* __restrict__ b1, ushort_t* __restrict__ x1_bf)
{
    const int bid = blockIdx.x;
    const int b = bid & 7;
    const int t = bid >> 3;                 // 0..1023
    const int nc = t >> 9;                  // 0/1
    const int rg = t & 511;                 // 8 rows per block
    const int wave = threadIdx.x >> 6, lane = threadIdx.x & 63;
    const int rsel = lane >> 5, li = lane & 31;
    const int m = b * SWAPS + rg * 8 + wave * 2 + rsel;
    const int4 iv = *(const int4*)(idx + (size_t)m * 4);
    const ushort_t* Pr = P2 + ((size_t)(b * 2 + nc) * NNODES) * 1024;
    const int col = li * 8;                 // within [0,256)

    float s[8];
    {
        const float* bp = b1 + nc * 256 + col;
        float4 ba = *(const float4*)bp;
        float4 bb = *(const float4*)(bp + 4);
        s[0] = ba.x; s[1] = ba.y; s[2] = ba.z; s[3] = ba.w;
        s[4] = bb.x; s[5] = bb.y; s[6] = bb.z; s[7] = bb.w;
    }
    const int nodes[4] = { iv.x, iv.y, iv.z, iv.w };
    #pragma unroll
    for (int sg = 0; sg < 4; ++sg) {
        us8 v = *(const us8*)(Pr + (size_t)nodes[sg] * 1024 + sg * 256 + col);
        #pragma unroll
        for (int u = 0; u < 8; ++u) s[u] += bf2f(v[u]);
    }
    us8 o;
    #pragma unroll
    for (int u = 0; u < 8; ++u)
        o[u] = f2bf(gelu_exact(s[u]));      // raw bf16 bits (FIX: no __bf16 value-conv)
    __builtin_nontemporal_store(o, (us8*)(x1_bf + (size_t)m * K2 + nc * 256 + col));
}

// ---------------------------------------------------------------------------
// GEMM2 + partial head: 128x128 tile, K=512, TWO K-tiles per barrier pair.
// Epilogue: partial[m] = sum_{cols} gelu(acc+b2)*W3 -> pp[half][m].
// ---------------------------------------------------------------------------
__global__ __launch_bounds__(256) void gemm2_partial(
    const ushort_t* __restrict__ x1_bf, const ushort_t* __restrict__ W2t,
    const float* __restrict__ b2, const float* __restrict__ W3,
    float* __restrict__ pp)
{
    __shared__ __align__(16) char smem[32768];

    const int tid = threadIdx.x;
    const int w = tid >> 6, lane = tid & 63;
    const int quad = lane >> 4, l16 = lane & 15;
    const int wr = w >> 1, wc = w & 1;
    const int m0 = blockIdx.y * 128, n0 = blockIdx.x * 128;

    const int row0 = tid >> 2, sub = tid & 3;
    const int cg = (sub - (row0 >> 1)) & 3;
    const ushort_t* bA0 = x1_bf + (size_t)(m0 + row0) * K2 + cg * 8;
    const ushort_t* bA1 = x1_bf + (size_t)(m0 + row0 + 64) * K2 + cg * 8;
    const ushort_t* bB0 = W2t + (size_t)(n0 + row0) * K2 + cg * 8;
    const ushort_t* bB1 = W2t + (size_t)(n0 + row0 + 64) * K2 + cg * 8;

    int pa[4], pb[4];
    #pragma unroll
    for (int i = 0; i < 4; ++i) {
        const int rA = wr * 64 + i * 16 + l16;
        const int rB = wc * 64 + i * 16 + l16;
        pa[i] = rA * 64 + (((quad + (rA >> 1)) & 3) * 16);
        pb[i] = 8192 + rB * 64 + (((quad + (rB >> 1)) & 3) * 16);
    }

    f32x4 acc[4][4] = {};

    auto stage = [&](int kt, int half) {
        const int oo = kt * 32;
        char* base = smem + half * 16384;
        glds16(bA0 + oo, base + w * 1024);
        glds16(bA1 + oo, base + 4096 + w * 1024);
        glds16(bB0 + oo, base + 8192 + w * 1024);
        glds16(bB1 + oo, base + 12288 + w * 1024);
    };
    auto compute = [&](int half) {
        const char* base = smem + half * 16384;
        bf16x8 af[4], bfr[4];
        #pragma unroll
        for (int i = 0; i < 4; ++i) {
            af[i]  = *(const bf16x8*)(base + pa[i]);
            bfr[i] = *(const bf16x8*)(base + pb[i]);
        }
        #pragma unroll
        for (int i = 0; i < 4; ++i)
            #pragma unroll
            for (int jj = 0; jj < 4; ++jj)
                acc[i][jj] = __builtin_amdgcn_mfma_f32_16x16x32_bf16(
                    af[i], bfr[jj], acc[i][jj], 0, 0, 0);
    };

    for (int kt = 0; kt < 16; kt += 2) {
        stage(kt, 0);
        stage(kt + 1, 1);
        __syncthreads();
        compute(0);
        compute(1);
        __syncthreads();
    }

    // ---- fused epilogue: partial head dot over this block's 128 cols ----
    float w3r[4], b2r[4];
    #pragma unroll
    for (int jj = 0; jj < 4; ++jj) {
        const int n = n0 + wc * 64 + jj * 16 + l16;
        w3r[jj] = W3[n];
        b2r[jj] = b2[n];
    }
    float part[4][4];
    #pragma unroll
    for (int i = 0; i < 4; ++i)
        #pragma unroll
        for (int rr = 0; rr < 4; ++rr) part[i][rr] = 0.0f;
    #pragma unroll
    for (int i = 0; i < 4; ++i)
        #pragma unroll
        for (int jj = 0; jj < 4; ++jj) {
            f32x4 v = acc[i][jj];
            #pragma unroll
            for (int rr = 0; rr < 4; ++rr)
                part[i][rr] = fmaf(gelu_exact(v[rr] + b2r[jj]), w3r[jj], part[i][rr]);
        }
    #pragma unroll
    for (int off = 1; off < 16; off <<= 1)
        #pragma unroll
        for (int i = 0; i < 4; ++i)
            #pragma unroll
            for (int rr = 0; rr < 4; ++rr)
                part[i][rr] += __shfl_xor(part[i][rr], off);

    float* red = (float*)smem;
    __syncthreads();
    if (wc == 1 && l16 == 0) {
        #pragma unroll
        for (int i = 0; i < 4; ++i)
            #pragma unroll
            for (int rr = 0; rr < 4; ++rr)
                red[wr * 64 + i * 16 + quad * 4 + rr] = part[i][rr];
    }
    __syncthreads();
    if (wc == 0 && l16 == 0) {
        float* dst = pp + (size_t)blockIdx.x * M_TOTAL + m0;
        #pragma unroll
        for (int i = 0; i < 4; ++i)
            #pragma unroll
            for (int rr = 0; rr < 4; ++rr) {
                const int r2 = wr * 64 + i * 16 + quad * 4 + rr;
                dst[r2] = part[i][rr] + red[r2];
            }
    }
}

// ---------------------------------------------------------------------------
// finalize: out[m] = softplus( pp[0][m] + pp[1][m] + b3 )
// ---------------------------------------------------------------------------
__global__ __launch_bounds__(256) void finalize_head(
    const float* __restrict__ pp, const float* __restrict__ b3,
    float* __restrict__ out)
{
    const int m = blockIdx.x * 256 + threadIdx.x;
    out[m] = softplus_f(pp[m] + pp[M_TOTAL + m] + b3[0]);
}

// ---------------------------------------------------------------------------
// Workspace (aliased; peak 96.25 MB):
//   P2    @ 0      : 64 MB  (dead after gather_sum)
//   pp    @ 0      : 256 KB (overlays dead P2)
//   h_bf  @ 64 MB  : 16 MB  (dead after gemm1_dense)
//   W1pt  @ 80 MB  :  2 MB  (dead after gemm1_dense)
//   x1_bf @ 64 MB  : 32 MB  (overlays dead h_bf/W1pt)
//   W2t   @ 96 MB  : 256 KB
// ---------------------------------------------------------------------------
extern "C" void kernel_launch(void* const* d_in, const int* in_sizes, int n_in,
                              void* d_out, int out_size, void* d_ws, size_t ws_size,
                              hipStream_t stream) {
    const float* h   = (const float*)d_in[0];
    const int*   idx = (const int*)d_in[1];
    const float* W1  = (const float*)d_in[2];
    const float* b1  = (const float*)d_in[3];
    const float* W2  = (const float*)d_in[4];
    const float* b2  = (const float*)d_in[5];
    const float* W3  = (const float*)d_in[6];
    const float* b3  = (const float*)d_in[7];
    float* out = (float*)d_out;

    char* ws = (char*)d_ws;
    ushort_t* P2    = (ushort_t*)ws;
    float*    pp    = (float*)ws;
    ushort_t* h_bf  = (ushort_t*)(ws + (64u << 20));
    ushort_t* W1pt  = (ushort_t*)(ws + (80u << 20));
    ushort_t* x1_bf = (ushort_t*)(ws + (64u << 20));
    ushort_t* W2t   = (ushort_t*)(ws + (96u << 20));

    convert_kernel<<<9344, 256, 0, stream>>>(h, W1, W2, h_bf, W1pt, W2t);
    gemm1_dense<<<2048, 256, 0, stream>>>(h_bf, W1pt, P2);
    gather_sum_kernel<<<8192, 256, 0, stream>>>(P2, idx, b1, x1_bf);
    gemm2_partial<<<dim3(N2 / 128, M_TOTAL / 128), 256, 0, stream>>>(x1_bf, W2t, b2, W3, pp);
    finalize_head<<<M_TOTAL / 256, 256, 0, stream>>>(pp, b3, out);
}

// Round 8
// 189.017 us; speedup vs baseline: 1.0788x; 1.0717x over previous
//
#include <hip/hip_runtime.h>
#include <math.h>

// Problem constants: B=8, N=2048, D=512, S=4096
#define BATCH 8
#define NNODES 2048
#define DDIM 512
#define SWAPS 4096
#define M_TOTAL (BATCH * SWAPS)   // 32768
#define KD DDIM                   // 512 (dense GEMM K)
#define K2 DDIM                   // 512
#define N2 (DDIM / 2)             // 256

typedef __attribute__((ext_vector_type(8))) __bf16 bf16x8;   // MFMA A/B frag
typedef __attribute__((ext_vector_type(4))) float f32x4;      // MFMA C/D frag
typedef __attribute__((ext_vector_type(8))) unsigned short us8;
typedef unsigned short ushort_t;

__device__ __forceinline__ float gelu_exact(float x) {
    return 0.5f * x * (1.0f + erff(x * 0.70710678118654752440f));
}
__device__ __forceinline__ float softplus_f(float x) {
    return fmaxf(x, 0.0f) + log1pf(expf(-fabsf(x)));
}
__device__ __forceinline__ unsigned short f2bf(float f) {
    unsigned int u = __builtin_bit_cast(unsigned int, f);
    u += 0x7FFFu + ((u >> 16) & 1u);
    return (unsigned short)(u >> 16);
}
__device__ __forceinline__ float bf2f(unsigned short s) {
    return __builtin_bit_cast(float, (unsigned int)s << 16);
}
__device__ __forceinline__ void glds16(const void* g, void* l) {
    __builtin_amdgcn_global_load_lds(
        (const __attribute__((address_space(1))) void*)g,
        (__attribute__((address_space(3))) void*)l, 16, 0, 0);
}

// ---------------------------------------------------------------------------
// convert: h -> h_bf (bf16);  W1[k][n] -> W1pt[j][d] bf16, j=(k/512)*512+n,
// d=k%512;  W2 -> W2t bf16 K-major.
// ---------------------------------------------------------------------------
__global__ __launch_bounds__(256) void convert_kernel(
    const float* __restrict__ h, const float* __restrict__ W1,
    const float* __restrict__ W2, ushort_t* __restrict__ h_bf,
    ushort_t* __restrict__ W1pt, ushort_t* __restrict__ W2t)
{
    const int bid = blockIdx.x;
    if (bid < 8192) {                       // h: 8M elems
        size_t i = ((size_t)bid * 256 + threadIdx.x) * 4;
        float4 v = *(const float4*)(h + i);
        ushort4 o = { f2bf(v.x), f2bf(v.y), f2bf(v.z), f2bf(v.w) };
        *(ushort4*)(h_bf + i) = o;
    } else if (bid < 8192 + 1024) {         // W1: 1M elems (2048 x 512 row-major)
        size_t e = ((size_t)(bid - 8192) * 256 + threadIdx.x) * 4;
        const int k = (int)(e >> 9), n = (int)(e & 511);
        const int sg = k >> 9, d = k & 511;
        const int j = sg * 512 + n;
        float4 v = *(const float4*)(W1 + e);
        W1pt[(size_t)(j + 0) * KD + d] = f2bf(v.x);
        W1pt[(size_t)(j + 1) * KD + d] = f2bf(v.y);
        W1pt[(size_t)(j + 2) * KD + d] = f2bf(v.z);
        W1pt[(size_t)(j + 3) * KD + d] = f2bf(v.w);
    } else {                                // W2: 131072 elems (512 x 256)
        size_t e = ((size_t)(bid - 9216) * 256 + threadIdx.x) * 4;
        const int k = (int)(e >> 8), n = (int)(e & 255);
        float4 v = *(const float4*)(W2 + e);
        W2t[(size_t)(n + 0) * K2 + k] = f2bf(v.x);
        W2t[(size_t)(n + 1) * K2 + k] = f2bf(v.y);
        W2t[(size_t)(n + 2) * K2 + k] = f2bf(v.z);
        W2t[(size_t)(n + 3) * K2 + k] = f2bf(v.w);
    }
}

// ---------------------------------------------------------------------------
// Dense GEMM1 (unchanged from r7): M=16384, N=2048, K=512; 128x128 tile;
// two BK=32 tiles per barrier pair. P2[b][nc][node][sg*256+pos]: per-(b,nc)
// region = 4MB = one XCD L2. XCD swizzle: bid&7 = batch.
// ---------------------------------------------------------------------------
__global__ __launch_bounds__(256) void gemm1_dense(
    const ushort_t* __restrict__ h_bf, const ushort_t* __restrict__ W1pt,
    ushort_t* __restrict__ P2)
{
    __shared__ __align__(16) char smem[32768];

    const int tid = threadIdx.x;
    const int w = tid >> 6, lane = tid & 63;
    const int quad = lane >> 4, l16 = lane & 15;
    const int wr = w >> 1, wc = w & 1;

    const int bid = blockIdx.x;
    const int xcd = bid & 7;            // == batch
    const int r = bid >> 3;
    const int m0 = xcd * NNODES + (r & 15) * 128;
    const int n0 = (r >> 4) * 128;

    const int row0 = tid >> 2, sub = tid & 3;
    const int cg = (sub - (row0 >> 1)) & 3;
    const ushort_t* bA0 = h_bf + (size_t)(m0 + row0) * KD + cg * 8;
    const ushort_t* bA1 = h_bf + (size_t)(m0 + row0 + 64) * KD + cg * 8;
    const ushort_t* bB0 = W1pt + (size_t)(n0 + row0) * KD + cg * 8;
    const ushort_t* bB1 = W1pt + (size_t)(n0 + row0 + 64) * KD + cg * 8;

    int pa[4], pb[4];
    #pragma unroll
    for (int i = 0; i < 4; ++i) {
        const int rA = wr * 64 + i * 16 + l16;
        const int rB = wc * 64 + i * 16 + l16;
        pa[i] = rA * 64 + (((quad + (rA >> 1)) & 3) * 16);
        pb[i] = 8192 + rB * 64 + (((quad + (rB >> 1)) & 3) * 16);
    }

    f32x4 acc[4][4] = {};

    auto stage = [&](int kt, int half) {
        const int oo = kt * 32;
        char* base = smem + half * 16384;
        glds16(bA0 + oo, base + w * 1024);
        glds16(bA1 + oo, base + 4096 + w * 1024);
        glds16(bB0 + oo, base + 8192 + w * 1024);
        glds16(bB1 + oo, base + 12288 + w * 1024);
    };
    auto compute = [&](int half) {
        const char* base = smem + half * 16384;
        bf16x8 af[4], bfr[4];
        #pragma unroll
        for (int i = 0; i < 4; ++i) {
            af[i]  = *(const bf16x8*)(base + pa[i]);
            bfr[i] = *(const bf16x8*)(base + pb[i]);
        }
        #pragma unroll
        for (int i = 0; i < 4; ++i)
            #pragma unroll
            for (int jj = 0; jj < 4; ++jj)
                acc[i][jj] = __builtin_amdgcn_mfma_f32_16x16x32_bf16(
                    af[i], bfr[jj], acc[i][jj], 0, 0, 0);
    };

    for (int kt = 0; kt < 16; kt += 2) {
        stage(kt, 0);
        stage(kt + 1, 1);
        __syncthreads();
        compute(0);
        compute(1);
        __syncthreads();
    }

    #pragma unroll
    for (int jj = 0; jj < 4; ++jj) {
        const int j = n0 + wc * 64 + jj * 16 + l16;
        const int sg = j >> 9, nh = j & 511;
        const size_t base = ((size_t)(xcd * 2 + (nh >> 8)) * NNODES) * 1024
                          + (size_t)(sg << 8) + (nh & 255);
        #pragma unroll
        for (int i = 0; i < 4; ++i) {
            f32x4 v = acc[i][jj];
            #pragma unroll
            for (int rr = 0; rr < 4; ++rr) {
                const int node = (m0 + wr * 64 + i * 16 + quad * 4 + rr) & (NNODES - 1);
                P2[base + (size_t)node * 1024] = f2bf(v[rr]);
            }
        }
    }
}

// ---------------------------------------------------------------------------
// FUSED gather + GEMM2 + head.
// Block: 64 swap-rows x full N2=256 cols, 512 threads (8 waves). Grid 512,
// XCD-pinned: bid&7 = batch b, m0 = b*4096 + (bid>>3)*64.
// Per BK=32 chunk (16 chunks):
//   waves 0-3: gather x1 tile [64][32] from P2 (4 seg reads + b1 + gelu ->
//              bf16) and ds_write into A staging (proven swizzled layout).
//   waves 4-7: glds16-stage W2t tile [256][32] (16KB).
//   1 barrier/chunk, dbuf (2 x 20KB).
// Wave (rf=w>>1, hf=w&1) computes rows rf*16.. x cols hf*128.. (8 frags).
// Epilogue: dot gelu(acc+b2) with W3 in-reg, shfl-reduce, LDS-combine the
// two col halves, softplus -> out. No x1, no pp, no extra launches.
// ---------------------------------------------------------------------------
__global__ __launch_bounds__(512) void fused_tail(
    const ushort_t* __restrict__ P2, const int* __restrict__ idx,
    const float* __restrict__ b1, const ushort_t* __restrict__ W2t,
    const float* __restrict__ b2, const float* __restrict__ W3,
    const float* __restrict__ b3, float* __restrict__ out)
{
    __shared__ __align__(16) char smem[40960];   // 2 x (A 4KB + B 16KB)

    const int tid = threadIdx.x;
    const int w = tid >> 6, lane = tid & 63;
    const int quad = lane >> 4, l16 = lane & 15;
    const int rf = w >> 1, hf = w & 1;

    const int bid = blockIdx.x;
    const int b = bid & 7;
    const int m0 = b * SWAPS + (bid >> 3) * 64;

    // ---- A-gather coords (waves 0-3 only use these) ----
    const int arow = tid >> 2;              // 0..63 (valid when tid<256)
    const int ap = tid & 3;                 // physical 16B chunk
    const int acg = (ap - (arow >> 1)) & 3; // global 16B chunk (swizzle)
    int4 iv = {0, 0, 0, 0};
    if (tid < 256) iv = *(const int4*)(idx + (size_t)(m0 + arow) * 4);
    const int nodes[4] = { iv.x, iv.y, iv.z, iv.w };
    const ushort_t* P2b = P2 + (size_t)(b * 2) * NNODES * 1024;

    // ---- B-staging coords (waves 4-7) ----
    const int vt = tid & 255;               // 0..255 within upper half
    const int brow0 = vt >> 2, bsub = vt & 3;
    const int bcg = (bsub - (brow0 >> 1)) & 3;
    const ushort_t* pB[4];
    #pragma unroll
    for (int g = 0; g < 4; ++g)
        pB[g] = W2t + (size_t)(g * 64 + brow0) * K2 + bcg * 8;

    // ---- fragment read offsets ----
    const int rA = rf * 16 + l16;
    const int paOff = rA * 64 + (((quad + (rA >> 1)) & 3) * 16);
    int pb[8];
    #pragma unroll
    for (int jf = 0; jf < 8; ++jf) {
        const int rB = hf * 128 + jf * 16 + l16;
        pb[jf] = 4096 + rB * 64 + (((quad + (rB >> 1)) & 3) * 16);
    }

    f32x4 acc[8] = {};

    auto stage = [&](int kc, int half) {
        char* base = smem + half * 20480;
        if (tid < 256) {
            // gather-compute A tile rows
            const int nc = kc >> 3;
            const int pos0 = (kc & 7) * 32 + acg * 8;
            const ushort_t* Pr = P2b + (size_t)nc * NNODES * 1024;
            us8 v0 = *(const us8*)(Pr + (size_t)nodes[0] * 1024 + 0 * 256 + pos0);
            us8 v1 = *(const us8*)(Pr + (size_t)nodes[1] * 1024 + 1 * 256 + pos0);
            us8 v2 = *(const us8*)(Pr + (size_t)nodes[2] * 1024 + 2 * 256 + pos0);
            us8 v3 = *(const us8*)(Pr + (size_t)nodes[3] * 1024 + 3 * 256 + pos0);
            const float* bp = b1 + nc * 256 + pos0;
            float4 ba = *(const float4*)bp;
            float4 bb = *(const float4*)(bp + 4);
            float s[8] = { ba.x, ba.y, ba.z, ba.w, bb.x, bb.y, bb.z, bb.w };
            #pragma unroll
            for (int e = 0; e < 8; ++e)
                s[e] += bf2f(v0[e]) + bf2f(v1[e]) + bf2f(v2[e]) + bf2f(v3[e]);
            us8 o;
            #pragma unroll
            for (int e = 0; e < 8; ++e) o[e] = f2bf(gelu_exact(s[e]));
            *(us8*)(base + arow * 64 + ap * 16) = o;
        } else {
            // stage B: 4 glds16 groups of 64 rows each
            const int oo = kc * 32;
            char* bbase = base + 4096;
            #pragma unroll
            for (int g = 0; g < 4; ++g)
                glds16(pB[g] + oo, bbase + g * 4096 + (w - 4) * 1024);
        }
    };
    auto compute = [&](int half) {
        const char* base = smem + half * 20480;
        bf16x8 af = *(const bf16x8*)(base + paOff);
        #pragma unroll
        for (int jf = 0; jf < 8; ++jf) {
            bf16x8 bfr = *(const bf16x8*)(base + pb[jf]);
            acc[jf] = __builtin_amdgcn_mfma_f32_16x16x32_bf16(af, bfr, acc[jf], 0, 0, 0);
        }
    };

    stage(0, 0);
    __syncthreads();
    for (int kc = 0; kc < 16; ++kc) {
        if (kc < 15) stage(kc + 1, (kc + 1) & 1);
        compute(kc & 1);
        __syncthreads();
    }

    // ---- epilogue: head dot over this wave's 128 cols ----
    float part[4] = {0.0f, 0.0f, 0.0f, 0.0f};
    #pragma unroll
    for (int jf = 0; jf < 8; ++jf) {
        const int n = hf * 128 + jf * 16 + l16;
        const float w3 = W3[n];
        const float bb2 = b2[n];
        f32x4 v = acc[jf];
        #pragma unroll
        for (int rr = 0; rr < 4; ++rr)
            part[rr] = fmaf(gelu_exact(v[rr] + bb2), w3, part[rr]);
    }
    #pragma unroll
    for (int off = 1; off < 16; off <<= 1)
        #pragma unroll
        for (int rr = 0; rr < 4; ++rr)
            part[rr] += __shfl_xor(part[rr], off);

    float* red = (float*)smem;
    if (hf == 1 && l16 == 0) {
        #pragma unroll
        for (int rr = 0; rr < 4; ++rr)
            red[rf * 16 + quad * 4 + rr] = part[rr];
    }
    __syncthreads();
    if (hf == 0 && l16 == 0) {
        const float bias3 = b3[0];
        #pragma unroll
        for (int rr = 0; rr < 4; ++rr) {
            const int r2 = rf * 16 + quad * 4 + rr;
            out[m0 + r2] = softplus_f(part[rr] + red[r2] + bias3);
        }
    }
}

// ---------------------------------------------------------------------------
// Workspace (peak 96.25 MB):
//   P2    @ 0      : 64 MB
//   h_bf  @ 64 MB  : 16 MB
//   W1pt  @ 80 MB  :  2 MB
//   W2t   @ 96 MB  : 256 KB
// ---------------------------------------------------------------------------
extern "C" void kernel_launch(void* const* d_in, const int* in_sizes, int n_in,
                              void* d_out, int out_size, void* d_ws, size_t ws_size,
                              hipStream_t stream) {
    const float* h   = (const float*)d_in[0];
    const int*   idx = (const int*)d_in[1];
    const float* W1  = (const float*)d_in[2];
    const float* b1  = (const float*)d_in[3];
    const float* W2  = (const float*)d_in[4];
    const float* b2  = (const float*)d_in[5];
    const float* W3  = (const float*)d_in[6];
    const float* b3  = (const float*)d_in[7];
    float* out = (float*)d_out;

    char* ws = (char*)d_ws;
    ushort_t* P2    = (ushort_t*)ws;
    ushort_t* h_bf  = (ushort_t*)(ws + (64u << 20));
    ushort_t* W1pt  = (ushort_t*)(ws + (80u << 20));
    ushort_t* W2t   = (ushort_t*)(ws + (96u << 20));

    convert_kernel<<<9344, 256, 0, stream>>>(h, W1, W2, h_bf, W1pt, W2t);
    gemm1_dense<<<2048, 256, 0, stream>>>(h_bf, W1pt, P2);
    fused_tail<<<512, 512, 0, stream>>>(P2, idx, b1, W2t, b2, W3, b3, out);
}

// Round 9
// 187.950 us; speedup vs baseline: 1.0849x; 1.0057x over previous
//
#include <hip/hip_runtime.h>
#include <math.h>

// Problem constants: B=8, N=2048, D=512, S=4096
#define BATCH 8
#define NNODES 2048
#define DDIM 512
#define SWAPS 4096
#define M_TOTAL (BATCH * SWAPS)   // 32768
#define KD DDIM                   // 512 (dense GEMM K)
#define K2 DDIM                   // 512
#define N2 (DDIM / 2)             // 256

typedef __attribute__((ext_vector_type(8))) __bf16 bf16x8;   // MFMA A/B frag
typedef __attribute__((ext_vector_type(4))) float f32x4;      // MFMA C/D frag
typedef __attribute__((ext_vector_type(8))) unsigned short us8;
typedef unsigned short ushort_t;

// tanh-approx GELU (max |err| vs exact erf-GELU ~5e-4; ~12 VALU inst vs ~50)
__device__ __forceinline__ float gelu_fast(float x) {
    const float u = 0.7978845608028654f * x * fmaf(0.044715f * x, x, 1.0f);
    const float e = __expf(-2.0f * fabsf(u));
    float t = (1.0f - e) / (1.0f + e);
    t = copysignf(t, u);
    return 0.5f * x * (1.0f + t);
}
__device__ __forceinline__ float softplus_f(float x) {
    return fmaxf(x, 0.0f) + log1pf(expf(-fabsf(x)));
}
__device__ __forceinline__ unsigned short f2bf(float f) {
    unsigned int u = __builtin_bit_cast(unsigned int, f);
    u += 0x7FFFu + ((u >> 16) & 1u);
    return (unsigned short)(u >> 16);
}
__device__ __forceinline__ float bf2f(unsigned short s) {
    return __builtin_bit_cast(float, (unsigned int)s << 16);
}
__device__ __forceinline__ void glds16(const void* g, void* l) {
    __builtin_amdgcn_global_load_lds(
        (const __attribute__((address_space(1))) void*)g,
        (__attribute__((address_space(3))) void*)l, 16, 0, 0);
}

// ---------------------------------------------------------------------------
// convert (weights only now): W1[k][n] -> W1pt[j][d] bf16, j=(k/512)*512+n,
// d=k%512;  W2 -> W2t bf16 K-major.  h is consumed as f32 directly by gemm1.
// ---------------------------------------------------------------------------
__global__ __launch_bounds__(256) void convert_kernel(
    const float* __restrict__ W1, const float* __restrict__ W2,
    ushort_t* __restrict__ W1pt, ushort_t* __restrict__ W2t)
{
    const int bid = blockIdx.x;
    if (bid < 1024) {                       // W1: 1M elems (2048 x 512 row-major)
        size_t e = ((size_t)bid * 256 + threadIdx.x) * 4;
        const int k = (int)(e >> 9), n = (int)(e & 511);
        const int sg = k >> 9, d = k & 511;
        const int j = sg * 512 + n;
        float4 v = *(const float4*)(W1 + e);
        W1pt[(size_t)(j + 0) * KD + d] = f2bf(v.x);
        W1pt[(size_t)(j + 1) * KD + d] = f2bf(v.y);
        W1pt[(size_t)(j + 2) * KD + d] = f2bf(v.z);
        W1pt[(size_t)(j + 3) * KD + d] = f2bf(v.w);
    } else {                                // W2: 131072 elems (512 x 256)
        size_t e = ((size_t)(bid - 1024) * 256 + threadIdx.x) * 4;
        const int k = (int)(e >> 8), n = (int)(e & 255);
        float4 v = *(const float4*)(W2 + e);
        W2t[(size_t)(n + 0) * K2 + k] = f2bf(v.x);
        W2t[(size_t)(n + 1) * K2 + k] = f2bf(v.y);
        W2t[(size_t)(n + 2) * K2 + k] = f2bf(v.z);
        W2t[(size_t)(n + 3) * K2 + k] = f2bf(v.w);
    }
}

// ---------------------------------------------------------------------------
// Dense GEMM1: M=16384, N=2048, K=512; 128x128 tile; two BK=32 tiles per
// barrier pair. A staged DIRECTLY from f32 h (float4x2 load + f2bf +
// ds_write_b128, same swizzled layout); B staged via glds16 from W1pt.
// P2[b][nc][node][sg*256+pos]: per-(b,nc) region = 4MB = one XCD L2.
// XCD swizzle: bid&7 = batch.
// ---------------------------------------------------------------------------
__global__ __launch_bounds__(256) void gemm1_dense(
    const float* __restrict__ h, const ushort_t* __restrict__ W1pt,
    ushort_t* __restrict__ P2)
{
    __shared__ __align__(16) char smem[32768];

    const int tid = threadIdx.x;
    const int w = tid >> 6, lane = tid & 63;
    const int quad = lane >> 4, l16 = lane & 15;
    const int wr = w >> 1, wc = w & 1;

    const int bid = blockIdx.x;
    const int xcd = bid & 7;            // == batch
    const int r = bid >> 3;
    const int m0 = xcd * NNODES + (r & 15) * 128;
    const int n0 = (r >> 4) * 128;

    const int row0 = tid >> 2, sub = tid & 3;
    const int cg = (sub - (row0 >> 1)) & 3;
    const float* fA0 = h + (size_t)(m0 + row0) * KD + cg * 8;        // f32
    const float* fA1 = h + (size_t)(m0 + row0 + 64) * KD + cg * 8;
    const ushort_t* bB0 = W1pt + (size_t)(n0 + row0) * KD + cg * 8;  // bf16
    const ushort_t* bB1 = W1pt + (size_t)(n0 + row0 + 64) * KD + cg * 8;

    int pa[4], pb[4];
    #pragma unroll
    for (int i = 0; i < 4; ++i) {
        const int rA = wr * 64 + i * 16 + l16;
        const int rB = wc * 64 + i * 16 + l16;
        pa[i] = rA * 64 + (((quad + (rA >> 1)) & 3) * 16);
        pb[i] = 8192 + rB * 64 + (((quad + (rB >> 1)) & 3) * 16);
    }

    f32x4 acc[4][4] = {};

    auto stageB = [&](int kt, int half) {
        const int oo = kt * 32;
        char* base = smem + half * 16384;
        glds16(bB0 + oo, base + 8192 + w * 1024);
        glds16(bB1 + oo, base + 12288 + w * 1024);
    };
    auto stageA = [&](int kt, int half) {
        char* base = smem + half * 16384;
        const float* p0 = fA0 + kt * 32;
        const float* p1 = fA1 + kt * 32;
        float4 a0 = *(const float4*)p0, a1 = *(const float4*)(p0 + 4);
        float4 c0 = *(const float4*)p1, c1 = *(const float4*)(p1 + 4);
        us8 oA, oB;
        oA[0] = f2bf(a0.x); oA[1] = f2bf(a0.y); oA[2] = f2bf(a0.z); oA[3] = f2bf(a0.w);
        oA[4] = f2bf(a1.x); oA[5] = f2bf(a1.y); oA[6] = f2bf(a1.z); oA[7] = f2bf(a1.w);
        oB[0] = f2bf(c0.x); oB[1] = f2bf(c0.y); oB[2] = f2bf(c0.z); oB[3] = f2bf(c0.w);
        oB[4] = f2bf(c1.x); oB[5] = f2bf(c1.y); oB[6] = f2bf(c1.z); oB[7] = f2bf(c1.w);
        *(us8*)(base + row0 * 64 + sub * 16) = oA;
        *(us8*)(base + 4096 + row0 * 64 + sub * 16) = oB;
    };
    auto compute = [&](int half) {
        const char* base = smem + half * 16384;
        bf16x8 af[4], bfr[4];
        #pragma unroll
        for (int i = 0; i < 4; ++i) {
            af[i]  = *(const bf16x8*)(base + pa[i]);
            bfr[i] = *(const bf16x8*)(base + pb[i]);
        }
        #pragma unroll
        for (int i = 0; i < 4; ++i)
            #pragma unroll
            for (int jj = 0; jj < 4; ++jj)
                acc[i][jj] = __builtin_amdgcn_mfma_f32_16x16x32_bf16(
                    af[i], bfr[jj], acc[i][jj], 0, 0, 0);
    };

    for (int kt = 0; kt < 16; kt += 2) {
        stageB(kt, 0);          // async first
        stageB(kt + 1, 1);
        stageA(kt, 0);          // VALU convert overlaps glds16
        stageA(kt + 1, 1);
        __syncthreads();
        compute(0);
        compute(1);
        __syncthreads();
    }

    // epilogue: write P2[(b*2+nc)][node][sg*256+pos]
    #pragma unroll
    for (int jj = 0; jj < 4; ++jj) {
        const int j = n0 + wc * 64 + jj * 16 + l16;
        const int sg = j >> 9, nh = j & 511;
        const size_t base = ((size_t)(xcd * 2 + (nh >> 8)) * NNODES) * 1024
                          + (size_t)(sg << 8) + (nh & 255);
        #pragma unroll
        for (int i = 0; i < 4; ++i) {
            f32x4 v = acc[i][jj];
            #pragma unroll
            for (int rr = 0; rr < 4; ++rr) {
                const int node = (m0 + wr * 64 + i * 16 + quad * 4 + rr) & (NNODES - 1);
                P2[base + (size_t)node * 1024] = f2bf(v[rr]);
            }
        }
    }
}

// ---------------------------------------------------------------------------
// FUSED gather + GEMM2 + head (r8 structure, gelu_fast).
// Block: 64 swap-rows x 256 cols, 512 threads (8 waves), grid 512, XCD-pinned.
// ---------------------------------------------------------------------------
__global__ __launch_bounds__(512) void fused_tail(
    const ushort_t* __restrict__ P2, const int* __restrict__ idx,
    const float* __restrict__ b1, const ushort_t* __restrict__ W2t,
    const float* __restrict__ b2, const float* __restrict__ W3,
    const float* __restrict__ b3, float* __restrict__ out)
{
    __shared__ __align__(16) char smem[40960];   // 2 x (A 4KB + B 16KB)

    const int tid = threadIdx.x;
    const int w = tid >> 6, lane = tid & 63;
    const int quad = lane >> 4, l16 = lane & 15;
    const int rf = w >> 1, hf = w & 1;

    const int bid = blockIdx.x;
    const int b = bid & 7;
    const int m0 = b * SWAPS + (bid >> 3) * 64;

    // A-gather coords (tid < 256)
    const int arow = tid >> 2;
    const int ap = tid & 3;
    const int acg = (ap - (arow >> 1)) & 3;
    int4 iv = {0, 0, 0, 0};
    if (tid < 256) iv = *(const int4*)(idx + (size_t)(m0 + arow) * 4);
    const int nodes[4] = { iv.x, iv.y, iv.z, iv.w };
    const ushort_t* P2b = P2 + (size_t)(b * 2) * NNODES * 1024;

    // B-staging coords (tid >= 256)
    const int vt = tid & 255;
    const int brow0 = vt >> 2, bsub = vt & 3;
    const int bcg = (bsub - (brow0 >> 1)) & 3;
    const ushort_t* pB[4];
    #pragma unroll
    for (int g = 0; g < 4; ++g)
        pB[g] = W2t + (size_t)(g * 64 + brow0) * K2 + bcg * 8;

    // fragment read offsets
    const int rA = rf * 16 + l16;
    const int paOff = rA * 64 + (((quad + (rA >> 1)) & 3) * 16);
    int pb[8];
    #pragma unroll
    for (int jf = 0; jf < 8; ++jf) {
        const int rB = hf * 128 + jf * 16 + l16;
        pb[jf] = 4096 + rB * 64 + (((quad + (rB >> 1)) & 3) * 16);
    }

    f32x4 acc[8] = {};

    auto stage = [&](int kc, int half) {
        char* base = smem + half * 20480;
        if (tid < 256) {
            const int nc = kc >> 3;
            const int pos0 = (kc & 7) * 32 + acg * 8;
            const ushort_t* Pr = P2b + (size_t)nc * NNODES * 1024;
            us8 v0 = *(const us8*)(Pr + (size_t)nodes[0] * 1024 + 0 * 256 + pos0);
            us8 v1 = *(const us8*)(Pr + (size_t)nodes[1] * 1024 + 1 * 256 + pos0);
            us8 v2 = *(const us8*)(Pr + (size_t)nodes[2] * 1024 + 2 * 256 + pos0);
            us8 v3 = *(const us8*)(Pr + (size_t)nodes[3] * 1024 + 3 * 256 + pos0);
            const float* bp = b1 + nc * 256 + pos0;
            float4 ba = *(const float4*)bp;
            float4 bb = *(const float4*)(bp + 4);
            float s[8] = { ba.x, ba.y, ba.z, ba.w, bb.x, bb.y, bb.z, bb.w };
            #pragma unroll
            for (int e = 0; e < 8; ++e)
                s[e] += bf2f(v0[e]) + bf2f(v1[e]) + bf2f(v2[e]) + bf2f(v3[e]);
            us8 o;
            #pragma unroll
            for (int e = 0; e < 8; ++e) o[e] = f2bf(gelu_fast(s[e]));
            *(us8*)(base + arow * 64 + ap * 16) = o;
        } else {
            const int oo = kc * 32;
            char* bbase = base + 4096;
            #pragma unroll
            for (int g = 0; g < 4; ++g)
                glds16(pB[g] + oo, bbase + g * 4096 + (w - 4) * 1024);
        }
    };
    auto compute = [&](int half) {
        const char* base = smem + half * 20480;
        bf16x8 af = *(const bf16x8*)(base + paOff);
        #pragma unroll
        for (int jf = 0; jf < 8; ++jf) {
            bf16x8 bfr = *(const bf16x8*)(base + pb[jf]);
            acc[jf] = __builtin_amdgcn_mfma_f32_16x16x32_bf16(af, bfr, acc[jf], 0, 0, 0);
        }
    };

    stage(0, 0);
    __syncthreads();
    for (int kc = 0; kc < 16; ++kc) {
        if (kc < 15) stage(kc + 1, (kc + 1) & 1);
        compute(kc & 1);
        __syncthreads();
    }

    // epilogue: head dot over this wave's 128 cols
    float part[4] = {0.0f, 0.0f, 0.0f, 0.0f};
    #pragma unroll
    for (int jf = 0; jf < 8; ++jf) {
        const int n = hf * 128 + jf * 16 + l16;
        const float w3 = W3[n];
        const float bb2 = b2[n];
        f32x4 v = acc[jf];
        #pragma unroll
        for (int rr = 0; rr < 4; ++rr)
            part[rr] = fmaf(gelu_fast(v[rr] + bb2), w3, part[rr]);
    }
    #pragma unroll
    for (int off = 1; off < 16; off <<= 1)
        #pragma unroll
        for (int rr = 0; rr < 4; ++rr)
            part[rr] += __shfl_xor(part[rr], off);

    float* red = (float*)smem;
    if (hf == 1 && l16 == 0) {
        #pragma unroll
        for (int rr = 0; rr < 4; ++rr)
            red[rf * 16 + quad * 4 + rr] = part[rr];
    }
    __syncthreads();
    if (hf == 0 && l16 == 0) {
        const float bias3 = b3[0];
        #pragma unroll
        for (int rr = 0; rr < 4; ++rr) {
            const int r2 = rf * 16 + quad * 4 + rr;
            out[m0 + r2] = softplus_f(part[rr] + red[r2] + bias3);
        }
    }
}

// ---------------------------------------------------------------------------
// Workspace (peak 66.25 MB):
//   P2    @ 0      : 64 MB
//   W1pt  @ 64 MB  :  2 MB
//   W2t   @ 66 MB  : 256 KB
// ---------------------------------------------------------------------------
extern "C" void kernel_launch(void* const* d_in, const int* in_sizes, int n_in,
                              void* d_out, int out_size, void* d_ws, size_t ws_size,
                              hipStream_t stream) {
    const float* h   = (const float*)d_in[0];
    const int*   idx = (const int*)d_in[1];
    const float* W1  = (const float*)d_in[2];
    const float* b1  = (const float*)d_in[3];
    const float* W2  = (const float*)d_in[4];
    const float* b2  = (const float*)d_in[5];
    const float* W3  = (const float*)d_in[6];
    const float* b3  = (const float*)d_in[7];
    float* out = (float*)d_out;

    char* ws = (char*)d_ws;
    ushort_t* P2    = (ushort_t*)ws;
    ushort_t* W1pt  = (ushort_t*)(ws + (64u << 20));
    ushort_t* W2t   = (ushort_t*)(ws + (66u << 20));

    convert_kernel<<<1152, 256, 0, stream>>>(W1, W2, W1pt, W2t);
    gemm1_dense<<<2048, 256, 0, stream>>>(h, W1pt, P2);
    fused_tail<<<512, 512, 0, stream>>>(P2, idx, b1, W2t, b2, W3, b3, out);
}

// Round 10
// 179.195 us; speedup vs baseline: 1.1379x; 1.0489x over previous
//
#include <hip/hip_runtime.h>
#include <math.h>

// Problem constants: B=8, N=2048, D=512, S=4096
#define BATCH 8
#define NNODES 2048
#define DDIM 512
#define SWAPS 4096
#define M_TOTAL (BATCH * SWAPS)   // 32768
#define KD DDIM                   // 512 (dense GEMM K)
#define K2 DDIM                   // 512
#define N2 (DDIM / 2)             // 256

typedef __attribute__((ext_vector_type(8))) __bf16 bf16x8;   // MFMA A/B frag
typedef __attribute__((ext_vector_type(4))) float f32x4;      // MFMA C/D frag
typedef __attribute__((ext_vector_type(8))) unsigned short us8;
typedef unsigned short ushort_t;

// tanh-approx GELU (max |err| vs exact erf-GELU ~5e-4; ~12 VALU inst vs ~50)
__device__ __forceinline__ float gelu_fast(float x) {
    const float u = 0.7978845608028654f * x * fmaf(0.044715f * x, x, 1.0f);
    const float e = __expf(-2.0f * fabsf(u));
    float t = (1.0f - e) / (1.0f + e);
    t = copysignf(t, u);
    return 0.5f * x * (1.0f + t);
}
__device__ __forceinline__ float softplus_f(float x) {
    return fmaxf(x, 0.0f) + log1pf(expf(-fabsf(x)));
}
__device__ __forceinline__ unsigned short f2bf(float f) {
    unsigned int u = __builtin_bit_cast(unsigned int, f);
    u += 0x7FFFu + ((u >> 16) & 1u);
    return (unsigned short)(u >> 16);
}
__device__ __forceinline__ float bf2f(unsigned short s) {
    return __builtin_bit_cast(float, (unsigned int)s << 16);
}
__device__ __forceinline__ void glds16(const void* g, void* l) {
    __builtin_amdgcn_global_load_lds(
        (const __attribute__((address_space(1))) void*)g,
        (__attribute__((address_space(3))) void*)l, 16, 0, 0);
}

// ---------------------------------------------------------------------------
// convert: h -> h_bf (bf16);  W1[k][n] -> W1pt[j][d] bf16 (j=(k/512)*512+n,
// d=k%512);  W2 -> W2f fragment-major: element (k,n) at
// [kc*8192 + n*32 + quad*8 + pos], kc=k/32, quad=(k%32)/8, pos=k%8.
// ---------------------------------------------------------------------------
__global__ __launch_bounds__(256) void convert_kernel(
    const float* __restrict__ h, const float* __restrict__ W1,
    const float* __restrict__ W2, ushort_t* __restrict__ h_bf,
    ushort_t* __restrict__ W1pt, ushort_t* __restrict__ W2f)
{
    const int bid = blockIdx.x;
    if (bid < 8192) {                       // h: 8M elems
        size_t i = ((size_t)bid * 256 + threadIdx.x) * 4;
        float4 v = *(const float4*)(h + i);
        ushort4 o = { f2bf(v.x), f2bf(v.y), f2bf(v.z), f2bf(v.w) };
        *(ushort4*)(h_bf + i) = o;
    } else if (bid < 8192 + 1024) {         // W1: 1M elems (2048 x 512 row-major)
        size_t e = ((size_t)(bid - 8192) * 256 + threadIdx.x) * 4;
        const int k = (int)(e >> 9), n = (int)(e & 511);
        const int sg = k >> 9, d = k & 511;
        const int j = sg * 512 + n;
        float4 v = *(const float4*)(W1 + e);
        W1pt[(size_t)(j + 0) * KD + d] = f2bf(v.x);
        W1pt[(size_t)(j + 1) * KD + d] = f2bf(v.y);
        W1pt[(size_t)(j + 2) * KD + d] = f2bf(v.z);
        W1pt[(size_t)(j + 3) * KD + d] = f2bf(v.w);
    } else {                                // W2: 131072 elems (512 x 256)
        size_t e = ((size_t)(bid - 9216) * 256 + threadIdx.x) * 4;
        const int k = (int)(e >> 8), n = (int)(e & 255);
        const int kc = k >> 5, quad = (k >> 3) & 3, pos = k & 7;
        const size_t base = (size_t)kc * 8192 + quad * 8 + pos;
        float4 v = *(const float4*)(W2 + e);
        W2f[base + (size_t)(n + 0) * 32] = f2bf(v.x);
        W2f[base + (size_t)(n + 1) * 32] = f2bf(v.y);
        W2f[base + (size_t)(n + 2) * 32] = f2bf(v.z);
        W2f[base + (size_t)(n + 3) * 32] = f2bf(v.w);
    }
}

// ---------------------------------------------------------------------------
// Dense GEMM1 (r7-proven, 51 us): M=16384, N=2048, K=512; 128x128 tile; two
// BK=32 tiles per barrier pair; glds16 staging of bf16 h_bf + W1pt.
// P2[b][nc][node][sg*256+pos]: per-(b,nc) region = 4MB = one XCD L2.
// XCD swizzle: bid&7 = batch.
// ---------------------------------------------------------------------------
__global__ __launch_bounds__(256) void gemm1_dense(
    const ushort_t* __restrict__ h_bf, const ushort_t* __restrict__ W1pt,
    ushort_t* __restrict__ P2)
{
    __shared__ __align__(16) char smem[32768];

    const int tid = threadIdx.x;
    const int w = tid >> 6, lane = tid & 63;
    const int quad = lane >> 4, l16 = lane & 15;
    const int wr = w >> 1, wc = w & 1;

    const int bid = blockIdx.x;
    const int xcd = bid & 7;            // == batch
    const int r = bid >> 3;
    const int m0 = xcd * NNODES + (r & 15) * 128;
    const int n0 = (r >> 4) * 128;

    const int row0 = tid >> 2, sub = tid & 3;
    const int cg = (sub - (row0 >> 1)) & 3;
    const ushort_t* bA0 = h_bf + (size_t)(m0 + row0) * KD + cg * 8;
    const ushort_t* bA1 = h_bf + (size_t)(m0 + row0 + 64) * KD + cg * 8;
    const ushort_t* bB0 = W1pt + (size_t)(n0 + row0) * KD + cg * 8;
    const ushort_t* bB1 = W1pt + (size_t)(n0 + row0 + 64) * KD + cg * 8;

    int pa[4], pb[4];
    #pragma unroll
    for (int i = 0; i < 4; ++i) {
        const int rA = wr * 64 + i * 16 + l16;
        const int rB = wc * 64 + i * 16 + l16;
        pa[i] = rA * 64 + (((quad + (rA >> 1)) & 3) * 16);
        pb[i] = 8192 + rB * 64 + (((quad + (rB >> 1)) & 3) * 16);
    }

    f32x4 acc[4][4] = {};

    auto stage = [&](int kt, int half) {
        const int oo = kt * 32;
        char* base = smem + half * 16384;
        glds16(bA0 + oo, base + w * 1024);
        glds16(bA1 + oo, base + 4096 + w * 1024);
        glds16(bB0 + oo, base + 8192 + w * 1024);
        glds16(bB1 + oo, base + 12288 + w * 1024);
    };
    auto compute = [&](int half) {
        const char* base = smem + half * 16384;
        bf16x8 af[4], bfr[4];
        #pragma unroll
        for (int i = 0; i < 4; ++i) {
            af[i]  = *(const bf16x8*)(base + pa[i]);
            bfr[i] = *(const bf16x8*)(base + pb[i]);
        }
        #pragma unroll
        for (int i = 0; i < 4; ++i)
            #pragma unroll
            for (int jj = 0; jj < 4; ++jj)
                acc[i][jj] = __builtin_amdgcn_mfma_f32_16x16x32_bf16(
                    af[i], bfr[jj], acc[i][jj], 0, 0, 0);
    };

    for (int kt = 0; kt < 16; kt += 2) {
        stage(kt, 0);
        stage(kt + 1, 1);
        __syncthreads();
        compute(0);
        compute(1);
        __syncthreads();
    }

    // epilogue: write P2[(b*2+nc)][node][sg*256+pos]
    #pragma unroll
    for (int jj = 0; jj < 4; ++jj) {
        const int j = n0 + wc * 64 + jj * 16 + l16;
        const int sg = j >> 9, nh = j & 511;
        const size_t base = ((size_t)(xcd * 2 + (nh >> 8)) * NNODES) * 1024
                          + (size_t)(sg << 8) + (nh & 255);
        #pragma unroll
        for (int i = 0; i < 4; ++i) {
            f32x4 v = acc[i][jj];
            #pragma unroll
            for (int rr = 0; rr < 4; ++rr) {
                const int node = (m0 + wr * 64 + i * 16 + quad * 4 + rr) & (NNODES - 1);
                P2[base + (size_t)node * 1024] = f2bf(v[rr]);
            }
        }
    }
}

// ---------------------------------------------------------------------------
// FUSED gather + GEMM2 + head, TWO-PHASE / ONE-BARRIER.
// Block: 64 swap-rows x 256 cols, 512 threads (8 waves), grid 512, XCD-pinned
// (bid&7 = batch).
// Phase 1: gather full 64x512 x1 tile -> LDS (64KB, swizzled 32-col chunks);
//   per thread 8 independent iters x 4 P2 loads (32 outstanding, no barriers).
// one __syncthreads.
// Phase 2 (barrier-free): wave (rg=w>>2, cg=w&3) computes rows rg*32..+31 x
//   cols cg*64..+63; A-frags ds_read_b128 (conflict-free swizzle), B-frags
//   DIRECT from global W2f (fragment-major, coalesced 16B/lane, L2-resident).
// Epilogue: in-reg head dot -> shfl over l16 -> LDS combine over 4 col-groups
//   -> softplus -> out.
// ---------------------------------------------------------------------------
__global__ __launch_bounds__(512) void fused_tail(
    const ushort_t* __restrict__ P2, const int* __restrict__ idx,
    const float* __restrict__ b1, const ushort_t* __restrict__ W2f,
    const float* __restrict__ b2, const float* __restrict__ W3,
    const float* __restrict__ b3, float* __restrict__ out)
{
    __shared__ __align__(16) char smem[66560];   // A 64KB + red 1KB

    const int tid = threadIdx.x;
    const int w = tid >> 6, lane = tid & 63;
    const int quad = lane >> 4, l16 = lane & 15;

    const int bid = blockIdx.x;
    const int b = bid & 7;
    const int m0 = b * SWAPS + (bid >> 3) * 64;

    // ---------------- Phase 1: gather x1 tile into LDS ----------------
    {
        const int row = tid >> 3;           // 0..63
        const int ws  = tid & 7;
        const int ap  = ws & 3;             // physical 16B chunk
        const int ncs = ws >> 2;            // 0/1 (which 256-col half)
        const int acg = (ap - (row >> 1)) & 3;   // global 16B chunk (swizzle)
        const int4 iv = *(const int4*)(idx + (size_t)(m0 + row) * 4);
        const ushort_t* Pr = P2 + (size_t)(b * 2 + ncs) * NNODES * 1024;
        const ushort_t* p0 = Pr + (size_t)iv.x * 1024 + 0 * 256;
        const ushort_t* p1 = Pr + (size_t)iv.y * 1024 + 1 * 256;
        const ushort_t* p2 = Pr + (size_t)iv.z * 1024 + 2 * 256;
        const ushort_t* p3 = Pr + (size_t)iv.w * 1024 + 3 * 256;
        #pragma unroll 4
        for (int it = 0; it < 8; ++it) {
            const int kc = ncs * 8 + it;
            const int pos0 = it * 32 + acg * 8;
            us8 v0 = *(const us8*)(p0 + pos0);
            us8 v1 = *(const us8*)(p1 + pos0);
            us8 v2 = *(const us8*)(p2 + pos0);
            us8 v3 = *(const us8*)(p3 + pos0);
            const float* bp = b1 + ncs * 256 + pos0;
            float4 ba = *(const float4*)bp;
            float4 bb = *(const float4*)(bp + 4);
            float s[8] = { ba.x, ba.y, ba.z, ba.w, bb.x, bb.y, bb.z, bb.w };
            #pragma unroll
            for (int e = 0; e < 8; ++e)
                s[e] += bf2f(v0[e]) + bf2f(v1[e]) + bf2f(v2[e]) + bf2f(v3[e]);
            us8 o;
            #pragma unroll
            for (int e = 0; e < 8; ++e) o[e] = f2bf(gelu_fast(s[e]));
            *(us8*)(smem + kc * 4096 + row * 64 + ap * 16) = o;
        }
    }
    __syncthreads();

    // ---------------- Phase 2: barrier-free MFMA ----------------
    const int rg = w >> 2, cg = w & 3;
    int paRow[2];
    #pragma unroll
    for (int i = 0; i < 2; ++i) {
        const int rA = rg * 32 + i * 16 + l16;
        paRow[i] = rA * 64 + (((quad + (rA >> 1)) & 3) * 16);
    }
    const ushort_t* Bbase = W2f + (size_t)(cg * 64 + l16) * 32 + quad * 8;

    f32x4 acc[2][4] = {};

    #pragma unroll 2
    for (int kc = 0; kc < 16; ++kc) {
        bf16x8 af0 = *(const bf16x8*)(smem + kc * 4096 + paRow[0]);
        bf16x8 af1 = *(const bf16x8*)(smem + kc * 4096 + paRow[1]);
        #pragma unroll
        for (int jf = 0; jf < 4; ++jf) {
            bf16x8 bfr = *(const bf16x8*)(Bbase + (size_t)kc * 8192 + jf * 512);
            acc[0][jf] = __builtin_amdgcn_mfma_f32_16x16x32_bf16(af0, bfr, acc[0][jf], 0, 0, 0);
            acc[1][jf] = __builtin_amdgcn_mfma_f32_16x16x32_bf16(af1, bfr, acc[1][jf], 0, 0, 0);
        }
    }

    // ---------------- epilogue: head dot ----------------
    float part[2][4] = {};
    #pragma unroll
    for (int jf = 0; jf < 4; ++jf) {
        const int n = cg * 64 + jf * 16 + l16;
        const float w3 = W3[n];
        const float bb2 = b2[n];
        #pragma unroll
        for (int i = 0; i < 2; ++i) {
            f32x4 v = acc[i][jf];
            #pragma unroll
            for (int rr = 0; rr < 4; ++rr)
                part[i][rr] = fmaf(gelu_fast(v[rr] + bb2), w3, part[i][rr]);
        }
    }
    #pragma unroll
    for (int off = 1; off < 16; off <<= 1)
        #pragma unroll
        for (int i = 0; i < 2; ++i)
            #pragma unroll
            for (int rr = 0; rr < 4; ++rr)
                part[i][rr] += __shfl_xor(part[i][rr], off);

    float* red = (float*)(smem + 65536);    // red[4][64]
    if (l16 == 0) {
        #pragma unroll
        for (int i = 0; i < 2; ++i)
            #pragma unroll
            for (int rr = 0; rr < 4; ++rr)
                red[cg * 64 + rg * 32 + i * 16 + quad * 4 + rr] = part[i][rr];
    }
    __syncthreads();
    if (tid < 64) {
        const float v = red[tid] + red[64 + tid] + red[128 + tid] + red[192 + tid];
        out[m0 + tid] = softplus_f(v + b3[0]);
    }
}

// ---------------------------------------------------------------------------
// Workspace (peak 82.25 MB):
//   P2    @ 0      : 64 MB
//   h_bf  @ 64 MB  : 16 MB
//   W1pt  @ 80 MB  :  2 MB
//   W2f   @ 82 MB  : 256 KB
// ---------------------------------------------------------------------------
extern "C" void kernel_launch(void* const* d_in, const int* in_sizes, int n_in,
                              void* d_out, int out_size, void* d_ws, size_t ws_size,
                              hipStream_t stream) {
    const float* h   = (const float*)d_in[0];
    const int*   idx = (const int*)d_in[1];
    const float* W1  = (const float*)d_in[2];
    const float* b1  = (const float*)d_in[3];
    const float* W2  = (const float*)d_in[4];
    const float* b2  = (const float*)d_in[5];
    const float* W3  = (const float*)d_in[6];
    const float* b3  = (const float*)d_in[7];
    float* out = (float*)d_out;

    char* ws = (char*)d_ws;
    ushort_t* P2    = (ushort_t*)ws;
    ushort_t* h_bf  = (ushort_t*)(ws + (64u << 20));
    ushort_t* W1pt  = (ushort_t*)(ws + (80u << 20));
    ushort_t* W2f   = (ushort_t*)(ws + (82u << 20));

    convert_kernel<<<9344, 256, 0, stream>>>(h, W1, W2, h_bf, W1pt, W2f);
    gemm1_dense<<<2048, 256, 0, stream>>>(h_bf, W1pt, P2);
    fused_tail<<<512, 512, 0, stream>>>(P2, idx, b1, W2f, b2, W3, b3, out);
}